// Round 1
// baseline (105.490 us; speedup 1.0000x reference)
//
#include <hip/hip_runtime.h>
#include <hip/hip_bf16.h>
#include <stdint.h>

#define NB 4
#define NN 2048
#define NF 128

typedef __attribute__((ext_vector_type(8))) short bf16x8;
typedef __attribute__((ext_vector_type(4))) short short4v;
typedef __attribute__((ext_vector_type(4))) float f32x4;

__device__ __forceinline__ short f2bf(float x) {
  __hip_bfloat16 h = __float2bfloat16(x);
  return *reinterpret_cast<short*>(&h);
}

__device__ __forceinline__ void gload_lds16(void* lds, const void* g) {
  __builtin_amdgcn_global_load_lds(
      (const __attribute__((address_space(1))) unsigned int*)(uintptr_t)g,
      (__attribute__((address_space(3))) unsigned int*)(uintptr_t)lds,
      16, 0, 0);
}

// ---------------- Kernel 1: row degree -> dinv = (deg+eps)^-1/2 ----------------
__global__ __launch_bounds__(256) void k_deg(const float* __restrict__ adj,
                                             float* __restrict__ dinv) {
  const int row = blockIdx.x;          // 0 .. NB*NN-1
  const int tid = threadIdx.x;
  const float4* p = (const float4*)(adj + (size_t)row * NN) + tid * 2;
  const float4 a = p[0], b = p[1];
  float s = a.x + a.y + a.z + a.w + b.x + b.y + b.z + b.w;
  for (int off = 32; off > 0; off >>= 1) s += __shfl_down(s, off);
  __shared__ float red[4];
  const int w = tid >> 6, lane = tid & 63;
  if (lane == 0) red[w] = s;
  __syncthreads();
  if (tid == 0) {
    const float d = red[0] + red[1] + red[2] + red[3];
    dinv[row] = rsqrtf(d + 1e-6f);
  }
}

// ---------------- Kernel 2: A_norm = dinv_i * adj * dinv_j  (bf16) ----------------
__global__ __launch_bounds__(256) void k_norm(const float* __restrict__ adj,
                                              const float* __restrict__ dinv,
                                              short* __restrict__ An) {
  const size_t gid = (size_t)blockIdx.x * 256 + threadIdx.x;
  const size_t e0 = gid * 8;
  const int b = (int)(e0 >> 22);          // N*N = 2^22
  const int rem = (int)(e0 & 0x3FFFFF);
  const int i = rem >> 11;
  const int j = rem & 2047;
  const float di = dinv[b * NN + i];
  const float4* pj = (const float4*)(dinv + b * NN + j);
  const float4 d0 = pj[0], d1 = pj[1];
  const float4* pa = (const float4*)(adj + e0);
  const float4 a0 = pa[0], a1 = pa[1];
  bf16x8 o;
  o[0] = f2bf(a0.x * di * d0.x);
  o[1] = f2bf(a0.y * di * d0.y);
  o[2] = f2bf(a0.z * di * d0.z);
  o[3] = f2bf(a0.w * di * d0.w);
  o[4] = f2bf(a1.x * di * d1.x);
  o[5] = f2bf(a1.y * di * d1.y);
  o[6] = f2bf(a1.z * di * d1.z);
  o[7] = f2bf(a1.w * di * d1.w);
  *(bf16x8*)(An + e0) = o;
}

// ---------------- Kernel 3: W -> W^T bf16 (all three layers) ----------------
__global__ __launch_bounds__(256) void k_wt(const float* __restrict__ W1,
                                            const float* __restrict__ W2,
                                            const float* __restrict__ W3,
                                            short* __restrict__ wt) {
  const int idx = blockIdx.x * 256 + threadIdx.x;   // 0 .. 3*16384-1
  const int w = idx >> 14;
  const int rem = idx & 16383;
  const int o = rem >> 7;
  const int f = rem & 127;
  const float* W = (w == 0) ? W1 : (w == 1) ? W2 : W3;
  wt[idx] = f2bf(W[f * NF + o]);   // wt[w][o][f] = W[f][o]
}

// ---------------- Kernel 4: g_T[b][o][j] = bf16( (h @ W)[j][o] ) ----------------
__global__ __launch_bounds__(256) void k_pre(const float* __restrict__ h,
                                             const short* __restrict__ wT,
                                             short* __restrict__ gT) {
  const int blk = blockIdx.x;            // 256 blocks: b = blk>>6, j0 = (blk&63)*32
  const int b = blk >> 6;
  const int j0 = (blk & 63) << 5;
  const int tid = threadIdx.x;
  const int w = tid >> 6, lane = tid & 63;
  const int lo = lane & 15, hi = lane >> 4;

  // A-operand: h rows (M=j, K=f), loaded f32 -> bf16 in-register
  bf16x8 af[2][4];
#pragma unroll
  for (int mm = 0; mm < 2; ++mm)
#pragma unroll
    for (int ks = 0; ks < 4; ++ks) {
      const int j = j0 + 16 * mm + lo;
      const int f = 32 * ks + hi * 8;
      const float4* p = (const float4*)(h + (size_t)(b * NN + j) * NF + f);
      const float4 x0 = p[0], x1 = p[1];
      bf16x8 v;
      v[0] = f2bf(x0.x); v[1] = f2bf(x0.y); v[2] = f2bf(x0.z); v[3] = f2bf(x0.w);
      v[4] = f2bf(x1.x); v[5] = f2bf(x1.y); v[6] = f2bf(x1.z); v[7] = f2bf(x1.w);
      af[mm][ks] = v;
    }

  f32x4 acc[2][2] = {};
#pragma unroll
  for (int ks = 0; ks < 4; ++ks) {
    bf16x8 wf[2];
#pragma unroll
    for (int nn = 0; nn < 2; ++nn) {
      const int o = 32 * w + 16 * nn + lo;
      const int f = 32 * ks + hi * 8;
      wf[nn] = *(const bf16x8*)(wT + o * NF + f);   // B[k=f][col=o] from W_T[o][f]
    }
#pragma unroll
    for (int mm = 0; mm < 2; ++mm)
#pragma unroll
      for (int nn = 0; nn < 2; ++nn)
        acc[mm][nn] = __builtin_amdgcn_mfma_f32_16x16x32_bf16(af[mm][ks], wf[nn],
                                                              acc[mm][nn], 0, 0, 0);
  }

  // store transposed: g_T[b][o][j], C/D layout col=lane&15, row=(lane>>4)*4+reg
#pragma unroll
  for (int mm = 0; mm < 2; ++mm)
#pragma unroll
    for (int nn = 0; nn < 2; ++nn) {
      const int o = 32 * w + 16 * nn + lo;
      const int j = j0 + 16 * mm + hi * 4;
      short4v v;
      v[0] = f2bf(acc[mm][nn][0]);
      v[1] = f2bf(acc[mm][nn][1]);
      v[2] = f2bf(acc[mm][nn][2]);
      v[3] = f2bf(acc[mm][nn][3]);
      *(short4v*)(gT + (size_t)(b * NF + o) * NN + j) = v;
    }
}

// ---------------- Kernel 5: z = A_norm @ g ; out = act(z+bias) + resid ----------------
// BM=32 rows, BN=128 (=F), BK=64. 4 waves, wave w owns cols [32w,32w+32).
// LDS per buffer: A tile 32x64 bf16 (4 KB) + G tile 128x64 bf16 (16 KB), rows 128 B,
// 16B-chunk XOR swizzle (chunk ^= row&7) applied on the pre-swizzled global source
// (linear global_load_lds dest) and on the ds_read side — both-sides (rule #21).
template <bool RELU>
__global__ __launch_bounds__(256) void k_agg(const short* __restrict__ An,
                                             const short* __restrict__ gT,
                                             const float* __restrict__ resid,
                                             const float* __restrict__ bias,
                                             float* __restrict__ out) {
  const int blk = blockIdx.x;            // 256: b = blk>>6, i0 = (blk&63)*32
  const int b = blk >> 6;
  const int i0 = (blk & 63) << 5;
  const int tid = threadIdx.x;
  const int w = tid >> 6, lane = tid & 63;
  const int lo = lane & 15, hi = lane >> 4;

  __shared__ __align__(16) char lds[2][20480];

  // staging source bases (pre-swizzled chunk within each 128 B tile row)
  const int rA = tid >> 3;                         // tile row 0..31
  const int scA = (tid & 7) ^ (rA & 7);            // source chunk
  const char* Arow = (const char*)An +
      ((size_t)b * NN * NN + (size_t)(i0 + rA) * NN) * 2 + scA * 16;
  const char* Grow[4];
#pragma unroll
  for (int p = 0; p < 4; ++p) {
    const int o = p * 32 + (tid >> 3);             // tile row 0..127
    const int sc = (tid & 7) ^ (o & 7);
    Grow[p] = (const char*)gT + (size_t)(b * NF + o) * NN * 2 + sc * 16;
  }

  // fragment ds_read offsets (swizzled)
  int offA[2][2], offG[2][2];
#pragma unroll
  for (int mm = 0; mm < 2; ++mm)
#pragma unroll
    for (int ks = 0; ks < 2; ++ks) {
      const int r = 16 * mm + lo;
      offA[mm][ks] = r * 128 + (((ks * 4 + hi) ^ (r & 7)) << 4);
    }
#pragma unroll
  for (int nn = 0; nn < 2; ++nn)
#pragma unroll
    for (int ks = 0; ks < 2; ++ks) {
      const int o = 32 * w + 16 * nn + lo;
      offG[nn][ks] = 4096 + o * 128 + (((ks * 4 + hi) ^ (o & 7)) << 4);
    }

  f32x4 acc[2][2] = {};

  // prologue: stage K-step 0 into buf0
  {
    char* nb = lds[0];
    gload_lds16(nb + tid * 16, Arow);
#pragma unroll
    for (int p = 0; p < 4; ++p)
      gload_lds16(nb + 4096 + p * 4096 + tid * 16, Grow[p]);
  }
  __syncthreads();

  const int NT = NN / 64;                // 32 K-steps
  for (int t = 0; t < NT; ++t) {
    const char* buf = lds[t & 1];
    if (t + 1 < NT) {                    // issue next-tile staging (async), overlaps MFMA
      char* nb = lds[(t + 1) & 1];
      const size_t joff = (size_t)(t + 1) * 128;   // 64 cols * 2 B
      gload_lds16(nb + tid * 16, Arow + joff);
#pragma unroll
      for (int p = 0; p < 4; ++p)
        gload_lds16(nb + 4096 + p * 4096 + tid * 16, Grow[p] + joff);
    }
    bf16x8 af[2][2], gf[2][2];
#pragma unroll
    for (int mm = 0; mm < 2; ++mm)
#pragma unroll
      for (int ks = 0; ks < 2; ++ks)
        af[mm][ks] = *(const bf16x8*)(buf + offA[mm][ks]);
#pragma unroll
    for (int nn = 0; nn < 2; ++nn)
#pragma unroll
      for (int ks = 0; ks < 2; ++ks)
        gf[nn][ks] = *(const bf16x8*)(buf + offG[nn][ks]);
#pragma unroll
    for (int ks = 0; ks < 2; ++ks)
#pragma unroll
      for (int mm = 0; mm < 2; ++mm)
#pragma unroll
        for (int nn = 0; nn < 2; ++nn)
          acc[mm][nn] = __builtin_amdgcn_mfma_f32_16x16x32_bf16(
              af[mm][ks], gf[nn][ks], acc[mm][nn], 0, 0, 0);
    __syncthreads();                     // drains vmcnt -> next buf ready
  }

  // epilogue: bias + (relu) + residual, fp32 out
#pragma unroll
  for (int nn = 0; nn < 2; ++nn) {
    const int o = 32 * w + 16 * nn + lo;
    const float bi = bias[o];
#pragma unroll
    for (int mm = 0; mm < 2; ++mm) {
#pragma unroll
      for (int r = 0; r < 4; ++r) {
        const int i = i0 + 16 * mm + hi * 4 + r;
        const size_t idx = (size_t)(b * NN + i) * NF + o;
        float z = acc[mm][nn][r] + bi;
        if (RELU) z = fmaxf(z, 0.0f);
        out[idx] = z + resid[idx];
      }
    }
  }
}

extern "C" void kernel_launch(void* const* d_in, const int* in_sizes, int n_in,
                              void* d_out, int out_size, void* d_ws, size_t ws_size,
                              hipStream_t stream) {
  const float* x   = (const float*)d_in[0];
  const float* adj = (const float*)d_in[1];
  const float* W1  = (const float*)d_in[2];
  const float* b1  = (const float*)d_in[3];
  const float* W2  = (const float*)d_in[4];
  const float* b2  = (const float*)d_in[5];
  const float* W3  = (const float*)d_in[6];
  const float* b3  = (const float*)d_in[7];
  float* out = (float*)d_out;
  char* ws = (char*)d_ws;

  // workspace layout (bytes), total ~42.2 MB
  float* dinv = (float*)(ws + 0);            // 32768
  short* wt   = (short*)(ws + 32768);        // 3*32768
  short* gT   = (short*)(ws + 131072);       // 2 MB
  float* h1   = (float*)(ws + 2228224);      // 4 MB
  float* h2   = (float*)(ws + 6422528);      // 4 MB
  short* An   = (short*)(ws + 10616832);     // 32 MB

  k_deg <<<NB * NN, 256, 0, stream>>>(adj, dinv);
  k_norm<<<(NB * NN * (size_t)NN) / 8 / 256, 256, 0, stream>>>(adj, dinv, An);
  k_wt  <<<192, 256, 0, stream>>>(W1, W2, W3, wt);

  // layer 1: h1 = relu(A@(x@W1)+b1) + x
  k_pre<<<256, 256, 0, stream>>>(x, wt, gT);
  k_agg<true><<<256, 256, 0, stream>>>(An, gT, x, b1, h1);
  // layer 2: h2 = relu(A@(h1@W2)+b2) + h1
  k_pre<<<256, 256, 0, stream>>>(h1, wt + 16384, gT);
  k_agg<true><<<256, 256, 0, stream>>>(An, gT, h1, b2, h2);
  // layer 3: out = A@(h2@W3)+b3 + h2
  k_pre<<<256, 256, 0, stream>>>(h2, wt + 32768, gT);
  k_agg<false><<<256, 256, 0, stream>>>(An, gT, h2, b3, out);
}

// Round 2
// 90.906 us; speedup vs baseline: 1.1604x; 1.1604x over previous
//
#include <hip/hip_runtime.h>
#include <hip/hip_bf16.h>
#include <stdint.h>

#define NB 4
#define NN 2048
#define NF 128

typedef __attribute__((ext_vector_type(8))) short bf16x8;
typedef __attribute__((ext_vector_type(4))) short short4v;
typedef __attribute__((ext_vector_type(4))) float f32x4;

__device__ __forceinline__ short f2bf(float x) {
  __hip_bfloat16 h = __float2bfloat16(x);
  return *reinterpret_cast<short*>(&h);
}
__device__ __forceinline__ float bf2f(short s) {
  unsigned int u = ((unsigned int)(unsigned short)s) << 16;
  return __uint_as_float(u);
}

__device__ __forceinline__ void gload_lds16(void* lds, const void* g) {
  __builtin_amdgcn_global_load_lds(
      (const __attribute__((address_space(1))) unsigned int*)(uintptr_t)g,
      (__attribute__((address_space(3))) unsigned int*)(uintptr_t)lds,
      16, 0, 0);
}

// ---------------- Kernel 1: row degree -> dinv = (deg+eps)^-1/2 ----------------
__global__ __launch_bounds__(256) void k_deg(const float* __restrict__ adj,
                                             float* __restrict__ dinv) {
  const int row = blockIdx.x;          // 0 .. NB*NN-1
  const int tid = threadIdx.x;
  const float4* p = (const float4*)(adj + (size_t)row * NN) + tid * 2;
  const float4 a = p[0], b = p[1];
  float s = a.x + a.y + a.z + a.w + b.x + b.y + b.z + b.w;
  for (int off = 32; off > 0; off >>= 1) s += __shfl_down(s, off);
  __shared__ float red[4];
  const int w = tid >> 6, lane = tid & 63;
  if (lane == 0) red[w] = s;
  __syncthreads();
  if (tid == 0) {
    const float d = red[0] + red[1] + red[2] + red[3];
    dinv[row] = rsqrtf(d + 1e-6f);
  }
}

// ---------------- Kernel 2: A_norm = dinv_i * adj * dinv_j  (bf16) ----------------
__global__ __launch_bounds__(256) void k_norm(const float* __restrict__ adj,
                                              const float* __restrict__ dinv,
                                              short* __restrict__ An) {
  const size_t gid = (size_t)blockIdx.x * 256 + threadIdx.x;
  const size_t e0 = gid * 8;
  const int b = (int)(e0 >> 22);          // N*N = 2^22
  const int rem = (int)(e0 & 0x3FFFFF);
  const int i = rem >> 11;
  const int j = rem & 2047;
  const float di = dinv[b * NN + i];
  const float4* pj = (const float4*)(dinv + b * NN + j);
  const float4 d0 = pj[0], d1 = pj[1];
  const float4* pa = (const float4*)(adj + e0);
  const float4 a0 = pa[0], a1 = pa[1];
  bf16x8 o;
  o[0] = f2bf(a0.x * di * d0.x);
  o[1] = f2bf(a0.y * di * d0.y);
  o[2] = f2bf(a0.z * di * d0.z);
  o[3] = f2bf(a0.w * di * d0.w);
  o[4] = f2bf(a1.x * di * d1.x);
  o[5] = f2bf(a1.y * di * d1.y);
  o[6] = f2bf(a1.z * di * d1.z);
  o[7] = f2bf(a1.w * di * d1.w);
  *(bf16x8*)(An + e0) = o;
}

// ---------------- Kernel 3: misc — xT = bf16(x^T) (blocks 0..63), wt = bf16(W^T) (64..66) ----
__global__ __launch_bounds__(256) void k_misc(const float* __restrict__ x,
                                              const float* __restrict__ W1,
                                              const float* __restrict__ W2,
                                              const float* __restrict__ W3,
                                              short* __restrict__ xT,
                                              short* __restrict__ wt) {
  const int bid = blockIdx.x;
  const int tid = threadIdx.x;
  if (bid < 64) {
    // transpose one [128 j][128 f] tile of x into xT[b][f][j] bf16
    const int b = bid >> 4;
    const int j0 = (bid & 15) << 7;
    __shared__ short tile[128 * 129];   // +1 short pad: column reads ~conflict-free
#pragma unroll
    for (int r = 0; r < 8; ++r) {
      const int j = 16 * r + (tid >> 4);
      const int f0 = (tid & 15) * 8;
      const float4* p = (const float4*)(x + ((size_t)(b * NN + j0 + j)) * NF + f0);
      const float4 a0 = p[0], a1 = p[1];
      short* t = tile + j * 129 + f0;
      t[0] = f2bf(a0.x); t[1] = f2bf(a0.y); t[2] = f2bf(a0.z); t[3] = f2bf(a0.w);
      t[4] = f2bf(a1.x); t[5] = f2bf(a1.y); t[6] = f2bf(a1.z); t[7] = f2bf(a1.w);
    }
    __syncthreads();
#pragma unroll
    for (int r = 0; r < 8; ++r) {
      const int f = 16 * r + (tid >> 4);
      const int jc = tid & 15;
      bf16x8 v;
#pragma unroll
      for (int q = 0; q < 8; ++q) v[q] = tile[(jc * 8 + q) * 129 + f];
      *(bf16x8*)(xT + ((size_t)(b * NF + f)) * NN + j0 + jc * 8) = v;
    }
  } else {
    const int wl = bid - 64;
    const float* W = (wl == 0) ? W1 : (wl == 1) ? W2 : W3;
#pragma unroll 4
    for (int r = 0; r < 64; ++r) {
      const int e = r * 256 + tid;
      const int o = e >> 7, f = e & 127;
      wt[wl * 16384 + e] = f2bf(W[f * NF + o]);   // wt[o][f] = W[f][o]
    }
  }
}

// ---------------- Kernel 4: fused layer ----------------
// y = A_norm @ h  (BM=32, BN=128, BK=128, 8 waves: 4 col-slices x 2 K-halves)
// then z = y @ W + bias (stage-2 MFMA, y split hi/lo bf16), relu?, + resid.
// Writes h_next f32 and (unless LAST) hT_next bf16.
template <bool LAST>
__global__ __launch_bounds__(512) void k_agg2(const short* __restrict__ An,
                                              const short* __restrict__ hT,
                                              const float* __restrict__ resid,
                                              const short* __restrict__ wT,
                                              const float* __restrict__ bias,
                                              float* __restrict__ outF,
                                              short* __restrict__ outT) {
  const int bid0 = blockIdx.x;
  const int bid = (bid0 & 7) * 32 + (bid0 >> 3);   // XCD-chunked swizzle (256 = 8*32)
  const int b = bid >> 6;
  const int i0 = (bid & 63) << 5;
  const int tid = threadIdx.x;
  const int w = tid >> 6, lane = tid & 63;
  const int lo = lane & 15, hi = lane >> 4;
  const int kg = w >> 2, wc = w & 3;

  __shared__ __align__(16) char lds[2][40960];   // per buf: A 32x128 (8K) + H 128x128 (32K)

  // stage-2 W fragments, issued early (L2-hot 32 KB): B[k=f][n=o] from wT[o][f]
  bf16x8 wfrag[4];
#pragma unroll
  for (int ks = 0; ks < 4; ++ks)
    wfrag[ks] = *(const bf16x8*)(wT + (16 * w + lo) * NF + ks * 32 + hi * 8);

  // staging sources (pre-swizzled 16B chunk within each 256 B tile row)
  const int rA = tid >> 4, cA = tid & 15;
  const short* Asrc = An + (size_t)(b * NN + i0 + rA) * NN + ((cA ^ (rA & 7)) * 8);
  const short* Hsrc[4];
#pragma unroll
  for (int p = 0; p < 4; ++p) {
    const int c = tid + 512 * p;
    const int f = c >> 4, ch = c & 15;
    Hsrc[p] = hT + (size_t)(b * NF + f) * NN + ((ch ^ (f & 7)) * 8);
  }

  // fragment ds_read offsets (swizzled); wave kg reads k-elems [kg*64, kg*64+64)
  int offA[2][2], offH[2][2];
#pragma unroll
  for (int mm = 0; mm < 2; ++mm)
#pragma unroll
    for (int ks = 0; ks < 2; ++ks) {
      const int r = 16 * mm + lo;
      const int ck = kg * 8 + ks * 4 + hi;
      offA[mm][ks] = r * 256 + ((ck ^ (r & 7)) << 4);
    }
#pragma unroll
  for (int nn = 0; nn < 2; ++nn)
#pragma unroll
    for (int ks = 0; ks < 2; ++ks) {
      const int f = 32 * wc + 16 * nn + lo;
      const int ck = kg * 8 + ks * 4 + hi;
      offH[nn][ks] = 8192 + f * 256 + ((ck ^ (f & 7)) << 4);
    }

  f32x4 acc[2][2] = {};

  // prologue: stage superstep 0 into buf0
  {
    char* nb = lds[0];
    gload_lds16(nb + tid * 16, Asrc);
#pragma unroll
    for (int p = 0; p < 4; ++p)
      gload_lds16(nb + 8192 + (tid + 512 * p) * 16, Hsrc[p]);
  }
  __syncthreads();

  const int NT = NN / 128;               // 16 supersteps
  for (int t = 0; t < NT; ++t) {
    if (t + 1 < NT) {
      char* nb = lds[(t + 1) & 1];
      const int koff = (t + 1) * 128;    // elements
      gload_lds16(nb + tid * 16, Asrc + koff);
#pragma unroll
      for (int p = 0; p < 4; ++p)
        gload_lds16(nb + 8192 + (tid + 512 * p) * 16, Hsrc[p] + koff);
    }
    const char* buf = lds[t & 1];
    bf16x8 af[2][2], hf[2][2];
#pragma unroll
    for (int mm = 0; mm < 2; ++mm)
#pragma unroll
      for (int ks = 0; ks < 2; ++ks)
        af[mm][ks] = *(const bf16x8*)(buf + offA[mm][ks]);
#pragma unroll
    for (int nn = 0; nn < 2; ++nn)
#pragma unroll
      for (int ks = 0; ks < 2; ++ks)
        hf[nn][ks] = *(const bf16x8*)(buf + offH[nn][ks]);
#pragma unroll
    for (int ks = 0; ks < 2; ++ks)
#pragma unroll
      for (int mm = 0; mm < 2; ++mm)
#pragma unroll
        for (int nn = 0; nn < 2; ++nn)
          acc[mm][nn] = __builtin_amdgcn_mfma_f32_16x16x32_bf16(
              af[mm][ks], hf[nn][ks], acc[mm][nn], 0, 0, 0);
    __syncthreads();
  }

  // ---- exchange: sum K-half partials, split y into bf16 hi+lo ----
  float* yp = (float*)lds;               // [2][32][128] f32 = 32 KB
#pragma unroll
  for (int mm = 0; mm < 2; ++mm)
#pragma unroll
    for (int nn = 0; nn < 2; ++nn) {
      const int f = 32 * wc + 16 * nn + lo;
      const int ib = 16 * mm + hi * 4;
#pragma unroll
      for (int r = 0; r < 4; ++r)
        yp[kg * 4096 + (ib + r) * 128 + f] = acc[mm][nn][r];
    }
  __syncthreads();
  {
    const int ii = tid >> 4;             // 0..31
    const int fc = tid & 15;             // 16B chunk
    const float4 s0 = *(const float4*)(yp + ii * 128 + fc * 8);
    const float4 s1 = *(const float4*)(yp + ii * 128 + fc * 8 + 4);
    const float4 t0 = *(const float4*)(yp + 4096 + ii * 128 + fc * 8);
    const float4 t1 = *(const float4*)(yp + 4096 + ii * 128 + fc * 8 + 4);
    float v[8] = {s0.x + t0.x, s0.y + t0.y, s0.z + t0.z, s0.w + t0.w,
                  s1.x + t1.x, s1.y + t1.y, s1.z + t1.z, s1.w + t1.w};
    bf16x8 vh, vl;
#pragma unroll
    for (int q = 0; q < 8; ++q) {
      vh[q] = f2bf(v[q]);
      vl[q] = f2bf(v[q] - bf2f(vh[q]));
    }
    const int ch = fc ^ (ii & 7);
    *(bf16x8*)((char*)lds + 32768 + ii * 256 + ch * 16) = vh;
    *(bf16x8*)((char*)lds + 40960 + ii * 256 + ch * 16) = vl;
  }
  __syncthreads();

  // ---- stage 2: z = y @ W ; wave w owns o-cols [16w, 16w+16) ----
  f32x4 acc2[2] = {};
#pragma unroll
  for (int ks = 0; ks < 4; ++ks) {
#pragma unroll
    for (int mm = 0; mm < 2; ++mm) {
      const int r = 16 * mm + lo;
      const int ck = (ks * 4 + hi) ^ (r & 7);
      const bf16x8 ahi = *(const bf16x8*)((char*)lds + 32768 + r * 256 + (ck << 4));
      const bf16x8 alo = *(const bf16x8*)((char*)lds + 40960 + r * 256 + (ck << 4));
      acc2[mm] = __builtin_amdgcn_mfma_f32_16x16x32_bf16(ahi, wfrag[ks], acc2[mm], 0, 0, 0);
      acc2[mm] = __builtin_amdgcn_mfma_f32_16x16x32_bf16(alo, wfrag[ks], acc2[mm], 0, 0, 0);
    }
  }

  // ---- epilogue: bias, relu?, residual; write f32 (+ bf16 transposed) ----
  const int o = 16 * w + lo;
  const float bi = bias[o];
#pragma unroll
  for (int mm = 0; mm < 2; ++mm) {
    const int ib = i0 + 16 * mm + hi * 4;
    float zr[4];
#pragma unroll
    for (int r = 0; r < 4; ++r) {
      float z = acc2[mm][r] + bi;
      if (!LAST) z = fmaxf(z, 0.0f);
      const size_t idx = (size_t)(b * NN + ib + r) * NF + o;
      zr[r] = z + resid[idx];
      outF[idx] = zr[r];
    }
    if (!LAST) {
      short4v v;
#pragma unroll
      for (int r = 0; r < 4; ++r) v[r] = f2bf(zr[r]);
      *(short4v*)(outT + (size_t)(b * NF + o) * NN + ib) = v;
    }
  }
}

extern "C" void kernel_launch(void* const* d_in, const int* in_sizes, int n_in,
                              void* d_out, int out_size, void* d_ws, size_t ws_size,
                              hipStream_t stream) {
  const float* x   = (const float*)d_in[0];
  const float* adj = (const float*)d_in[1];
  const float* W1  = (const float*)d_in[2];
  const float* b1  = (const float*)d_in[3];
  const float* W2  = (const float*)d_in[4];
  const float* b2  = (const float*)d_in[5];
  const float* W3  = (const float*)d_in[6];
  const float* b3  = (const float*)d_in[7];
  float* out = (float*)d_out;
  char* ws = (char*)d_ws;

  // workspace layout (bytes), total ~48.4 MB
  float* dinv = (float*)(ws + 0);              // 32 KB
  short* wt   = (short*)(ws + 32768);          // 3 * 32 KB
  short* hT0  = (short*)(ws + 131072);         // 2 MB  (bf16 x^T)
  short* hT1  = (short*)(ws + 2228224);        // 2 MB
  short* hT2  = (short*)(ws + 4325376);        // 2 MB
  float* h1   = (float*)(ws + 6422528);        // 4 MB
  float* h2   = (float*)(ws + 10616832);       // 4 MB
  short* An   = (short*)(ws + 14811136);       // 32 MB

  k_deg <<<NB * NN, 256, 0, stream>>>(adj, dinv);
  k_norm<<<8192, 256, 0, stream>>>(adj, dinv, An);
  k_misc<<<67, 256, 0, stream>>>(x, W1, W2, W3, hT0, wt);

  k_agg2<false><<<256, 512, 0, stream>>>(An, hT0, x,  wt,         b1, h1,  hT1);
  k_agg2<false><<<256, 512, 0, stream>>>(An, hT1, h1, wt + 16384, b2, h2,  hT2);
  k_agg2<true> <<<256, 512, 0, stream>>>(An, hT2, h2, wt + 32768, b3, out, nullptr);
}